// Round 14
// baseline (96.154 us; speedup 1.0000x reference)
//
#include <hip/hip_runtime.h>
#include <hip/hip_bf16.h>

typedef __attribute__((ext_vector_type(8))) short short8;
typedef __attribute__((ext_vector_type(4))) short short4v;
typedef __attribute__((ext_vector_type(2))) int   int2v;
typedef __attribute__((ext_vector_type(4))) float floatx4;

#define BATCH 16
#define SEQ   2048
#define DIM   64
#define QSCALE 0.18033688011112042f   /* 0.125 * log2(e) : softmax in exp2 domain */
#define WS_NEED (9u*1024u*1024u)

__device__ __forceinline__ unsigned short f2bf(float f) {
    return __builtin_bit_cast(unsigned short, __float2bfloat16(f));
}

#if defined(__has_builtin)
#if __has_builtin(__builtin_amdgcn_exp2f)
#define EXP2(x) __builtin_amdgcn_exp2f(x)
#endif
#endif
#ifndef EXP2
#define EXP2(x) exp2f(x)
#endif

#define MFMA32(A,B,C) __builtin_amdgcn_mfma_f32_16x16x32_bf16(A,B,C,0,0,0)

#if defined(__has_builtin)
#if __has_builtin(__builtin_amdgcn_mfma_f32_16x16x16bf16_1k)
#define MFMA16(A,B,C) __builtin_amdgcn_mfma_f32_16x16x16bf16_1k(A,B,C,0,0,0)
#elif __has_builtin(__builtin_amdgcn_mfma_f32_16x16x16_bf16)
#define MFMA16(A,B,C) __builtin_amdgcn_mfma_f32_16x16x16_bf16(A,B,C,0,0,0)
#endif
#endif
#ifndef MFMA16
__device__ __forceinline__ floatx4 mfma16_asm(short4v a, short4v b, floatx4 c) {
    asm volatile("s_nop 1\n\tv_mfma_f32_16x16x16_bf16 %0, %1, %2, %0"
                 : "+v"(c) : "v"(a), "v"(b));
    return c;
}
#define MFMA16(A,B,C) mfma16_asm(A,B,C)
#endif

// light barrier: LDS-visibility drain only (global loads stay in flight).
// TWO per iteration for the pipelined read-of-previous-parity body (R9
// proved one is insufficient).
#define LIGHT_BARRIER()                                        \
    do {                                                       \
        asm volatile("s_waitcnt lgkmcnt(0)" ::: "memory");     \
        __builtin_amdgcn_s_barrier();                          \
        __builtin_amdgcn_sched_barrier(0);                     \
    } while (0)

// ---------------- convert K,V -> bf16 frag layouts + zero d_out ----------------
// Kw [16][128 t16][2 st][64 l][8p] = K[b][t16*16+a][st*32+g*8+p]   (a=l&15,g=l>>4)
// Vw [16][128 kt][64 l][4 dt][4p] = V[b][kt*16+g*4+p][dt*16+a]
// Q is NOT converted here: dpa_main loads fp32 Q once per block (R14).
// Also zeroes Og (atomic merge target) -> no separate memset dispatch.
__global__ __launch_bounds__(256)
void convert_kv(const float* __restrict__ K, const float* __restrict__ V,
                unsigned short* __restrict__ ws, float* __restrict__ Og) {
    const int t = blockIdx.x * 256 + threadIdx.x;   // 0..393215

    // zero d_out: 2097152 floats = 524288 float4
    for (unsigned u = (unsigned)t; u < 524288u; u += 393216u)
        ((floatx4*)Og)[u] = (floatx4)0.0f;

    if (t < 262144) {                               // K region
        const int r = t;
        const int b = r >> 14;
        const int rem = r & 16383;
        const int t16 = rem >> 7;
        const int st  = (rem >> 6) & 1;
        const int l   = rem & 63;
        const int a = l & 15, g = l >> 4;
        const float* src = K + ((size_t)(b * SEQ + t16 * 16 + a)) * DIM + st * 32 + g * 8;
        short8 o;
        #pragma unroll
        for (int p = 0; p < 8; ++p) o[p] = (short)f2bf(src[p]);
        *(short8*)(ws + (size_t)r * 8) = o;
    } else {                                        // V region
        const int r = t - 262144;                   // 0..131071 = [b][kt][l]
        const int b  = r >> 13;
        const int kt = (r >> 6) & 127;
        const int l  = r & 63;
        const int a = l & 15, g = l >> 4;
        const float* src = V + ((size_t)(b * SEQ + kt * 16 + g * 4)) * DIM + a;
        short8 o0, o1;
        #pragma unroll
        for (int dt = 0; dt < 2; ++dt)
            #pragma unroll
            for (int p = 0; p < 4; ++p)
                o0[dt * 4 + p] = (short)f2bf(src[(size_t)p * DIM + dt * 16]);
        #pragma unroll
        for (int dt = 2; dt < 4; ++dt)
            #pragma unroll
            for (int p = 0; p < 4; ++p)
                o1[(dt - 2) * 4 + p] = (short)f2bf(src[(size_t)p * DIM + dt * 16]);
        unsigned short* dst = ws + 2097152 + (size_t)r * 16;
        *(short8*)(dst)     = o0;
        *(short8*)(dst + 8) = o1;
    }
}

// ---------------- main: softmax-over-batch attention, 1-tile pipeline ----
// (R10 structure verbatim -- the measured best. Only change: Q loaded as
// fp32 directly and converted in-register in the prologue.)
// grid 512 = 128 q-tiles(16) x 4 k-chunks(512). block 512 = 8 waves = 8
// batch-pairs. Swapped QK^T (mfma(K,Q)) puts P^T[k=g*4+r][q=a] in registers ==
// A-frag of 16x16x16 PV. Per iter: V(t-1) loads issue, QK(t)+exp(t)+write(t),
// light barrier, combine(t-1)+pack(t-1)+PV(t-1), light barrier.
// Exchange layout [64 l][12] dwords: b128 reads conflict-free, writes 2-way.
__global__ __launch_bounds__(512)
void dpa_main(const float* __restrict__ Qg, const unsigned short* __restrict__ Kw,
              const unsigned short* __restrict__ Vw, float* __restrict__ Og) {
    __shared__ __align__(16) float dl[2][4][64][12];   // 24 KB

    const int tid = threadIdx.x;
    const int l = tid & 63;
    const int w = tid >> 6;            // batch-pair 0..7
    const int a = l & 15, g = l >> 4;
    const int bx = blockIdx.x;
    const int ch = bx & 3;
    const int qt = bx >> 2;
    const int b0 = w * 2;
    const int wsw = w ^ (l >> 3);      // slot swizzle (sum is perm-invariant)

    const unsigned short* Kb = Kw + (size_t)b0 * 131072 + l * 8;
    const unsigned short* Vb = Vw + (size_t)b0 * 131072 + l * 16;

    // Q fragments: load fp32 directly, convert+scale in-register (one-time)
    short8 Qf[2][2];
    #pragma unroll
    for (int bb = 0; bb < 2; ++bb) {
        #pragma unroll
        for (int st = 0; st < 2; ++st) {
            const float* src = Qg + ((size_t)((b0 + bb) * SEQ + qt * 16 + a)) * DIM
                                  + st * 32 + g * 8;
            const float4 f0 = *(const float4*)(src);
            const float4 f1 = *(const float4*)(src + 4);
            short8 q;
            q[0] = (short)f2bf(f0.x * QSCALE); q[1] = (short)f2bf(f0.y * QSCALE);
            q[2] = (short)f2bf(f0.z * QSCALE); q[3] = (short)f2bf(f0.w * QSCALE);
            q[4] = (short)f2bf(f1.x * QSCALE); q[5] = (short)f2bf(f1.y * QSCALE);
            q[6] = (short)f2bf(f1.z * QSCALE); q[7] = (short)f2bf(f1.w * QSCALE);
            Qf[bb][st] = q;
        }
    }

    // K fragments for tile 0
    short8 Kf[2][2];
    #pragma unroll
    for (int bb = 0; bb < 2; ++bb)
        #pragma unroll
        for (int st = 0; st < 2; ++st)
            Kf[bb][st] = *(const short8*)(Kb + bb * 131072 + (ch * 32) * 1024 + st * 512);

    floatx4 O[2][4];
    #pragma unroll
    for (int bb = 0; bb < 2; ++bb)
        #pragma unroll
        for (int dt = 0; dt < 4; ++dt) O[bb][dt] = (floatx4)0.0f;

    floatx4 SA[2], SB[2];

#define QKEXP(T, SOUT)                                                        \
    __builtin_amdgcn_s_setprio(1);                                            \
    {                                                                         \
        floatx4 s0 = (floatx4)0.0f, s1 = (floatx4)0.0f;                       \
        s0 = MFMA32(Kf[0][0], Qf[0][0], s0);                                  \
        s0 = MFMA32(Kf[0][1], Qf[0][1], s0);                                  \
        s1 = MFMA32(Kf[1][0], Qf[1][0], s1);                                  \
        s1 = MFMA32(Kf[1][1], Qf[1][1], s1);                                  \
        SOUT[0] = s0; SOUT[1] = s1;                                           \
    }                                                                         \
    __builtin_amdgcn_s_setprio(0);                                            \
    {                                                                         \
        const int ktn_ = ch * 32 + (((T) < 31) ? (T) + 1 : 31);               \
        Kf[0][0] = *(const short8*)(Kb + 0 * 131072 + ktn_ * 1024);           \
        Kf[0][1] = *(const short8*)(Kb + 0 * 131072 + ktn_ * 1024 + 512);     \
        Kf[1][0] = *(const short8*)(Kb + 1 * 131072 + ktn_ * 1024);           \
        Kf[1][1] = *(const short8*)(Kb + 1 * 131072 + ktn_ * 1024 + 512);     \
    }                                                                         \
    _Pragma("unroll")                                                         \
    for (int r = 0; r < 4; ++r) {                                             \
        const float e0 = EXP2(SOUT[0][r]);                                    \
        const float e1 = EXP2(SOUT[1][r]);                                    \
        SOUT[0][r] = e0; SOUT[1][r] = e1;                                     \
        dl[(T) & 1][r][l][wsw] = e0 + e1;                                     \
    }

#define COMBINE_PV(T, SPREV, v01_0, v23_0, v01_1, v23_1)                      \
    {                                                                         \
        float fr_[4];                                                         \
        _Pragma("unroll")                                                     \
        for (int r = 0; r < 4; ++r) {                                         \
            const floatx4 u0 = *(const floatx4*)&dl[((T)-1) & 1][r][l][0];    \
            const floatx4 u1 = *(const floatx4*)&dl[((T)-1) & 1][r][l][4];    \
            const floatx4 us = u0 + u1;                                       \
            fr_[r] = __builtin_amdgcn_rcpf((us[0] + us[1]) + (us[2] + us[3]));\
        }                                                                     \
        _Pragma("unroll")                                                     \
        for (int bb = 0; bb < 2; ++bb) {                                      \
            const short8 v01 = (bb == 0) ? v01_0 : v01_1;                     \
            const short8 v23 = (bb == 0) ? v23_0 : v23_1;                     \
            const unsigned int c0 = __builtin_bit_cast(unsigned int, SPREV[bb][0] * fr_[0]) + 0x8000u; \
            const unsigned int c1 = __builtin_bit_cast(unsigned int, SPREV[bb][1] * fr_[1]) + 0x8000u; \
            const unsigned int c2 = __builtin_bit_cast(unsigned int, SPREV[bb][2] * fr_[2]) + 0x8000u; \
            const unsigned int c3 = __builtin_bit_cast(unsigned int, SPREV[bb][3] * fr_[3]) + 0x8000u; \
            int2v pp;                                                         \
            pp[0] = (int)__builtin_amdgcn_perm(c1, c0, 0x07060302u);          \
            pp[1] = (int)__builtin_amdgcn_perm(c3, c2, 0x07060302u);          \
            const short4v af = __builtin_bit_cast(short4v, pp);               \
            const short4v b0v = __builtin_shufflevector(v01, v01, 0, 1, 2, 3);\
            const short4v b1v = __builtin_shufflevector(v01, v01, 4, 5, 6, 7);\
            const short4v b2v = __builtin_shufflevector(v23, v23, 0, 1, 2, 3);\
            const short4v b3v = __builtin_shufflevector(v23, v23, 4, 5, 6, 7);\
            __builtin_amdgcn_s_setprio(1);                                    \
            O[bb][0] = MFMA16(af, b0v, O[bb][0]);                             \
            O[bb][1] = MFMA16(af, b1v, O[bb][1]);                             \
            O[bb][2] = MFMA16(af, b2v, O[bb][2]);                             \
            O[bb][3] = MFMA16(af, b3v, O[bb][3]);                             \
            __builtin_amdgcn_s_setprio(0);                                    \
        }                                                                     \
    }

#define BODY(T, SOUT, SPREV)                                                  \
    {                                                                         \
        const int ktp_ = ch * 32 + (T) - 1;                                   \
        const unsigned short* vp0_ = Vb + 0 * 131072 + ktp_ * 1024;           \
        const unsigned short* vp1_ = Vb + 1 * 131072 + ktp_ * 1024;           \
        const short8 V01_0_ = *(const short8*)(vp0_);                         \
        const short8 V23_0_ = *(const short8*)(vp0_ + 8);                     \
        const short8 V01_1_ = *(const short8*)(vp1_);                         \
        const short8 V23_1_ = *(const short8*)(vp1_ + 8);                     \
        QKEXP(T, SOUT)                                                        \
        LIGHT_BARRIER();                                                      \
        COMBINE_PV(T, SPREV, V01_0_, V23_0_, V01_1_, V23_1_)                  \
        LIGHT_BARRIER();                                                      \
    }

    // ---- prologue: tile 0 (QK/exp/write only) ----
    QKEXP(0, SA)

    // ---- main loop: tiles 1..31 (parity-static S rotation) ----
    #pragma unroll 1
    for (int j = 0; j < 15; ++j) {
        const int t1 = 2 * j + 1;
        BODY(t1, SB, SA)
        BODY(t1 + 1, SA, SB)
    }
    BODY(31, SB, SA)

    // ---- epilogue: PV for tile 31 ----
    {
        const int ktp = ch * 32 + 31;
        const unsigned short* vp0 = Vb + 0 * 131072 + ktp * 1024;
        const unsigned short* vp1 = Vb + 1 * 131072 + ktp * 1024;
        const short8 V01_0 = *(const short8*)(vp0);
        const short8 V23_0 = *(const short8*)(vp0 + 8);
        const short8 V01_1 = *(const short8*)(vp1);
        const short8 V23_1 = *(const short8*)(vp1 + 8);
        COMBINE_PV(32, SB, V01_0, V23_0, V01_1, V23_1)
    }

    // guard MFMA->VALU read (needed for asm fallback; cheap otherwise)
    asm volatile("s_nop 7\n\ts_nop 7" :::);

    // ---- merge k-chunk partials ----
    #pragma unroll
    for (int bb = 0; bb < 2; ++bb)
        #pragma unroll
        for (int dt = 0; dt < 4; ++dt)
            #pragma unroll
            for (int r = 0; r < 4; ++r)
                unsafeAtomicAdd(Og + ((size_t)((b0 + bb) * SEQ + qt * 16 + g * 4 + r)) * DIM
                                    + dt * 16 + a,
                                O[bb][dt][r]);
#undef BODY
#undef COMBINE_PV
#undef QKEXP
}

// ---------------- fallback (ws too small): naive fp32 ----------------
__global__ __launch_bounds__(512)
void dpa_naive(const float* __restrict__ Q, const float* __restrict__ K,
               const float* __restrict__ V, float* __restrict__ out) {
    __shared__ float attn_lds[BATCH][8][64];
    const int tid = threadIdx.x;
    const int lane_k = tid & 63, row_q = tid >> 6, lane_d = tid & 63;
    const int q0 = blockIdx.x * 8;
    float acc[BATCH];
    #pragma unroll
    for (int b = 0; b < BATCH; ++b) acc[b] = 0.0f;
    for (int k0 = 0; k0 < SEQ; k0 += 64) {
        float s[BATCH];
        #pragma unroll
        for (int b = 0; b < BATCH; ++b) {
            const float4* qrow = (const float4*)(Q + ((size_t)b * SEQ + (q0 + row_q)) * DIM);
            const float4* krow = (const float4*)(K + ((size_t)b * SEQ + (k0 + lane_k)) * DIM);
            float a0 = 0.f;
            #pragma unroll
            for (int d4 = 0; d4 < 16; ++d4) {
                float4 qa = qrow[d4]; float4 kb = krow[d4];
                a0 += qa.x*kb.x + qa.y*kb.y + qa.z*kb.z + qa.w*kb.w;
            }
            s[b] = a0 * 0.125f;
        }
        float m = s[0];
        #pragma unroll
        for (int b = 1; b < BATCH; ++b) m = fmaxf(m, s[b]);
        float den = 0.f;
        #pragma unroll
        for (int b = 0; b < BATCH; ++b) { s[b] = __expf(s[b] - m); den += s[b]; }
        const float inv = 1.0f / den;
        #pragma unroll
        for (int b = 0; b < BATCH; ++b) attn_lds[b][row_q][lane_k] = s[b] * inv;
        __syncthreads();
        #pragma unroll
        for (int b = 0; b < BATCH; ++b) {
            const float* vbase = V + ((size_t)b * SEQ + k0) * DIM + lane_d;
            float acc2 = 0.f;
            #pragma unroll 8
            for (int kk = 0; kk < 64; ++kk) acc2 += attn_lds[b][row_q][kk] * vbase[(size_t)kk * DIM];
            acc[b] += acc2;
        }
        __syncthreads();
    }
    #pragma unroll
    for (int b = 0; b < BATCH; ++b)
        out[((size_t)b * SEQ + (q0 + row_q)) * DIM + lane_d] = acc[b];
}

extern "C" void kernel_launch(void* const* d_in, const int* in_sizes, int n_in,
                              void* d_out, int out_size, void* d_ws, size_t ws_size,
                              hipStream_t stream) {
    const float* Q = (const float*)d_in[0];
    const float* K = (const float*)d_in[1];
    const float* V = (const float*)d_in[2];
    float* out = (float*)d_out;

    if (ws_size < WS_NEED) {
        dpa_naive<<<dim3(SEQ / 8), dim3(512), 0, stream>>>(Q, K, V, out);
        return;
    }
    unsigned short* ws = (unsigned short*)d_ws;
    convert_kv<<<dim3(1536), dim3(256), 0, stream>>>(K, V, ws, out);
    dpa_main<<<dim3(512), dim3(512), 0, stream>>>(Q, ws, ws + 2097152, out);
}

// Round 15
// 78.967 us; speedup vs baseline: 1.2176x; 1.2176x over previous
//
#include <hip/hip_runtime.h>
#include <hip/hip_bf16.h>

typedef __attribute__((ext_vector_type(8))) short short8;
typedef __attribute__((ext_vector_type(4))) short short4v;
typedef __attribute__((ext_vector_type(2))) int   int2v;
typedef __attribute__((ext_vector_type(4))) float floatx4;

#define BATCH 16
#define SEQ   2048
#define DIM   64
#define QSCALE 0.18033688011112042f   /* 0.125 * log2(e) : softmax in exp2 domain */
#define WS_NEED (12u*1024u*1024u)

__device__ __forceinline__ unsigned short f2bf(float f) {
    return __builtin_bit_cast(unsigned short, __float2bfloat16(f));
}

#if defined(__has_builtin)
#if __has_builtin(__builtin_amdgcn_exp2f)
#define EXP2(x) __builtin_amdgcn_exp2f(x)
#endif
#endif
#ifndef EXP2
#define EXP2(x) exp2f(x)
#endif

#define MFMA32(A,B,C) __builtin_amdgcn_mfma_f32_16x16x32_bf16(A,B,C,0,0,0)

#if defined(__has_builtin)
#if __has_builtin(__builtin_amdgcn_mfma_f32_16x16x16bf16_1k)
#define MFMA16(A,B,C) __builtin_amdgcn_mfma_f32_16x16x16bf16_1k(A,B,C,0,0,0)
#elif __has_builtin(__builtin_amdgcn_mfma_f32_16x16x16_bf16)
#define MFMA16(A,B,C) __builtin_amdgcn_mfma_f32_16x16x16_bf16(A,B,C,0,0,0)
#endif
#endif
#ifndef MFMA16
__device__ __forceinline__ floatx4 mfma16_asm(short4v a, short4v b, floatx4 c) {
    asm volatile("s_nop 1\n\tv_mfma_f32_16x16x16_bf16 %0, %1, %2, %0"
                 : "+v"(c) : "v"(a), "v"(b));
    return c;
}
#define MFMA16(A,B,C) mfma16_asm(A,B,C)
#endif

// light barrier: LDS-visibility drain only (global loads stay in flight).
// TWO per iteration for the pipelined read-of-previous-parity body (R9
// proved one is insufficient).
#define LIGHT_BARRIER()                                        \
    do {                                                       \
        asm volatile("s_waitcnt lgkmcnt(0)" ::: "memory");     \
        __builtin_amdgcn_s_barrier();                          \
        __builtin_amdgcn_sched_barrier(0);                     \
    } while (0)

// ---------------- convert: fp32 -> bf16 MFMA-frag layouts + zero d_out ----
// Qw [16][128 t16][2 st][64 l][8p] = Q[b][t16*16+a][st*32+g*8+p] * QSCALE  (a=l&15,g=l>>4)
// Kw same (scale 1).
// Vw [16][128 kt][64 l][4 dt][4p] = V[b][kt*16+g*4+p][dt*16+a]   (B frag for 16x16x16)
// Also zeroes Og (atomic merge target) -> no separate memset dispatch.
__global__ __launch_bounds__(256)
void convert_kernel(const float* __restrict__ Q, const float* __restrict__ K,
                    const float* __restrict__ V, unsigned short* __restrict__ ws,
                    float* __restrict__ Og) {
    const int t = blockIdx.x * 256 + threadIdx.x;   // 0..655359

    // zero d_out: 2097152 floats = 524288 float4 (threads 0..524287 do one)
    if (t < 524288)
        ((floatx4*)Og)[t] = (floatx4)0.0f;

    if (t < 524288) {
        const int region = t >> 18;                 // 0=Q 1=K
        const int r = t & 262143;
        const int b = r >> 14;
        const int rem = r & 16383;
        const int t16 = rem >> 7;
        const int st  = (rem >> 6) & 1;
        const int l   = rem & 63;
        const int a = l & 15, g = l >> 4;
        const float* src = (region == 0 ? Q : K) +
            ((size_t)(b * SEQ + t16 * 16 + a)) * DIM + st * 32 + g * 8;
        const float s = (region == 0) ? QSCALE : 1.0f;
        short8 o;
        #pragma unroll
        for (int p = 0; p < 8; ++p) o[p] = (short)f2bf(src[p] * s);
        *(short8*)(ws + (size_t)region * 2097152 + (size_t)r * 8) = o;
    } else {
        const int r = t - 524288;                   // 0..131071 = [b][kt][l]
        const int b  = r >> 13;
        const int kt = (r >> 6) & 127;
        const int l  = r & 63;
        const int a = l & 15, g = l >> 4;
        const float* src = V + ((size_t)(b * SEQ + kt * 16 + g * 4)) * DIM + a;
        short8 o0, o1;
        #pragma unroll
        for (int dt = 0; dt < 2; ++dt)
            #pragma unroll
            for (int p = 0; p < 4; ++p)
                o0[dt * 4 + p] = (short)f2bf(src[(size_t)p * DIM + dt * 16]);
        #pragma unroll
        for (int dt = 2; dt < 4; ++dt)
            #pragma unroll
            for (int p = 0; p < 4; ++p)
                o1[(dt - 2) * 4 + p] = (short)f2bf(src[(size_t)p * DIM + dt * 16]);
        unsigned short* dst = ws + 4194304 + (size_t)r * 16;
        *(short8*)(dst)     = o0;
        *(short8*)(dst + 8) = o1;
    }
}

// ---------------- main: softmax-over-batch attention, 1-tile pipeline ----
// (R10 structure verbatim -- the measured best: 68.7-68.9 us across 3 runs.)
// grid 512 = 128 q-tiles(16) x 4 k-chunks(512). block 512 = 8 waves = 8
// batch-pairs. Swapped QK^T (mfma(K,Q)) puts P^T[k=g*4+r][q=a] in registers ==
// A-frag of 16x16x16 PV. Per iter: V(t-1) loads issue, QK(t)+exp(t)+write(t),
// light barrier, combine(t-1)+pack(t-1)+PV(t-1), light barrier. Global loads
// stay in flight across both barriers (no vmcnt drain).
// Exchange layout [64 l][12] dwords: b128 reads conflict-free, writes 2-way.
__global__ __launch_bounds__(512)
void dpa_main(const unsigned short* __restrict__ Qw, const unsigned short* __restrict__ Kw,
              const unsigned short* __restrict__ Vw, float* __restrict__ Og) {
    __shared__ __align__(16) float dl[2][4][64][12];   // 24 KB

    const int tid = threadIdx.x;
    const int l = tid & 63;
    const int w = tid >> 6;            // batch-pair 0..7
    const int a = l & 15, g = l >> 4;
    const int bx = blockIdx.x;
    const int ch = bx & 3;
    const int qt = bx >> 2;
    const int b0 = w * 2;
    const int wsw = w ^ (l >> 3);      // slot swizzle (sum is perm-invariant)

    const unsigned short* Kb = Kw + (size_t)b0 * 131072 + l * 8;
    const unsigned short* Vb = Vw + (size_t)b0 * 131072 + l * 16;

    // Q fragments in registers (iteration-invariant)
    short8 Qf[2][2];
    {
        const unsigned short* Qb = Qw + (size_t)b0 * 131072 + qt * 1024 + l * 8;
        #pragma unroll
        for (int bb = 0; bb < 2; ++bb)
            #pragma unroll
            for (int st = 0; st < 2; ++st)
                Qf[bb][st] = *(const short8*)(Qb + bb * 131072 + st * 512);
    }

    // K fragments for tile 0
    short8 Kf[2][2];
    #pragma unroll
    for (int bb = 0; bb < 2; ++bb)
        #pragma unroll
        for (int st = 0; st < 2; ++st)
            Kf[bb][st] = *(const short8*)(Kb + bb * 131072 + (ch * 32) * 1024 + st * 512);

    floatx4 O[2][4];
    #pragma unroll
    for (int bb = 0; bb < 2; ++bb)
        #pragma unroll
        for (int dt = 0; dt < 4; ++dt) O[bb][dt] = (floatx4)0.0f;

    floatx4 SA[2], SB[2];

#define QKEXP(T, SOUT)                                                        \
    __builtin_amdgcn_s_setprio(1);                                            \
    {                                                                         \
        floatx4 s0 = (floatx4)0.0f, s1 = (floatx4)0.0f;                       \
        s0 = MFMA32(Kf[0][0], Qf[0][0], s0);                                  \
        s0 = MFMA32(Kf[0][1], Qf[0][1], s0);                                  \
        s1 = MFMA32(Kf[1][0], Qf[1][0], s1);                                  \
        s1 = MFMA32(Kf[1][1], Qf[1][1], s1);                                  \
        SOUT[0] = s0; SOUT[1] = s1;                                           \
    }                                                                         \
    __builtin_amdgcn_s_setprio(0);                                            \
    {                                                                         \
        const int ktn_ = ch * 32 + (((T) < 31) ? (T) + 1 : 31);               \
        Kf[0][0] = *(const short8*)(Kb + 0 * 131072 + ktn_ * 1024);           \
        Kf[0][1] = *(const short8*)(Kb + 0 * 131072 + ktn_ * 1024 + 512);     \
        Kf[1][0] = *(const short8*)(Kb + 1 * 131072 + ktn_ * 1024);           \
        Kf[1][1] = *(const short8*)(Kb + 1 * 131072 + ktn_ * 1024 + 512);     \
    }                                                                         \
    _Pragma("unroll")                                                         \
    for (int r = 0; r < 4; ++r) {                                             \
        const float e0 = EXP2(SOUT[0][r]);                                    \
        const float e1 = EXP2(SOUT[1][r]);                                    \
        SOUT[0][r] = e0; SOUT[1][r] = e1;                                     \
        dl[(T) & 1][r][l][wsw] = e0 + e1;                                     \
    }

#define COMBINE_PV(T, SPREV, v01_0, v23_0, v01_1, v23_1)                      \
    {                                                                         \
        float fr_[4];                                                         \
        _Pragma("unroll")                                                     \
        for (int r = 0; r < 4; ++r) {                                         \
            const floatx4 u0 = *(const floatx4*)&dl[((T)-1) & 1][r][l][0];    \
            const floatx4 u1 = *(const floatx4*)&dl[((T)-1) & 1][r][l][4];    \
            const floatx4 us = u0 + u1;                                       \
            fr_[r] = __builtin_amdgcn_rcpf((us[0] + us[1]) + (us[2] + us[3]));\
        }                                                                     \
        _Pragma("unroll")                                                     \
        for (int bb = 0; bb < 2; ++bb) {                                      \
            const short8 v01 = (bb == 0) ? v01_0 : v01_1;                     \
            const short8 v23 = (bb == 0) ? v23_0 : v23_1;                     \
            const unsigned int c0 = __builtin_bit_cast(unsigned int, SPREV[bb][0] * fr_[0]) + 0x8000u; \
            const unsigned int c1 = __builtin_bit_cast(unsigned int, SPREV[bb][1] * fr_[1]) + 0x8000u; \
            const unsigned int c2 = __builtin_bit_cast(unsigned int, SPREV[bb][2] * fr_[2]) + 0x8000u; \
            const unsigned int c3 = __builtin_bit_cast(unsigned int, SPREV[bb][3] * fr_[3]) + 0x8000u; \
            int2v pp;                                                         \
            pp[0] = (int)__builtin_amdgcn_perm(c1, c0, 0x07060302u);          \
            pp[1] = (int)__builtin_amdgcn_perm(c3, c2, 0x07060302u);          \
            const short4v af = __builtin_bit_cast(short4v, pp);               \
            const short4v b0v = __builtin_shufflevector(v01, v01, 0, 1, 2, 3);\
            const short4v b1v = __builtin_shufflevector(v01, v01, 4, 5, 6, 7);\
            const short4v b2v = __builtin_shufflevector(v23, v23, 0, 1, 2, 3);\
            const short4v b3v = __builtin_shufflevector(v23, v23, 4, 5, 6, 7);\
            __builtin_amdgcn_s_setprio(1);                                    \
            O[bb][0] = MFMA16(af, b0v, O[bb][0]);                             \
            O[bb][1] = MFMA16(af, b1v, O[bb][1]);                             \
            O[bb][2] = MFMA16(af, b2v, O[bb][2]);                             \
            O[bb][3] = MFMA16(af, b3v, O[bb][3]);                             \
            __builtin_amdgcn_s_setprio(0);                                    \
        }                                                                     \
    }

#define BODY(T, SOUT, SPREV)                                                  \
    {                                                                         \
        const int ktp_ = ch * 32 + (T) - 1;                                   \
        const unsigned short* vp0_ = Vb + 0 * 131072 + ktp_ * 1024;           \
        const unsigned short* vp1_ = Vb + 1 * 131072 + ktp_ * 1024;           \
        const short8 V01_0_ = *(const short8*)(vp0_);                         \
        const short8 V23_0_ = *(const short8*)(vp0_ + 8);                     \
        const short8 V01_1_ = *(const short8*)(vp1_);                         \
        const short8 V23_1_ = *(const short8*)(vp1_ + 8);                     \
        QKEXP(T, SOUT)                                                        \
        LIGHT_BARRIER();                                                      \
        COMBINE_PV(T, SPREV, V01_0_, V23_0_, V01_1_, V23_1_)                  \
        LIGHT_BARRIER();                                                      \
    }

    // ---- prologue: tile 0 (QK/exp/write only) ----
    QKEXP(0, SA)

    // ---- main loop: tiles 1..31 (parity-static S rotation) ----
    #pragma unroll 1
    for (int j = 0; j < 15; ++j) {
        const int t1 = 2 * j + 1;
        BODY(t1, SB, SA)
        BODY(t1 + 1, SA, SB)
    }
    BODY(31, SB, SA)

    // ---- epilogue: PV for tile 31 ----
    {
        const int ktp = ch * 32 + 31;
        const unsigned short* vp0 = Vb + 0 * 131072 + ktp * 1024;
        const unsigned short* vp1 = Vb + 1 * 131072 + ktp * 1024;
        const short8 V01_0 = *(const short8*)(vp0);
        const short8 V23_0 = *(const short8*)(vp0 + 8);
        const short8 V01_1 = *(const short8*)(vp1);
        const short8 V23_1 = *(const short8*)(vp1 + 8);
        COMBINE_PV(32, SB, V01_0, V23_0, V01_1, V23_1)
    }

    // guard MFMA->VALU read (needed for asm fallback; cheap otherwise)
    asm volatile("s_nop 7\n\ts_nop 7" :::);

    // ---- merge k-chunk partials ----
    #pragma unroll
    for (int bb = 0; bb < 2; ++bb)
        #pragma unroll
        for (int dt = 0; dt < 4; ++dt)
            #pragma unroll
            for (int r = 0; r < 4; ++r)
                unsafeAtomicAdd(Og + ((size_t)((b0 + bb) * SEQ + qt * 16 + g * 4 + r)) * DIM
                                    + dt * 16 + a,
                                O[bb][dt][r]);
#undef BODY
#undef COMBINE_PV
#undef QKEXP
}

// ---------------- fallback (ws too small): naive fp32 ----------------
__global__ __launch_bounds__(512)
void dpa_naive(const float* __restrict__ Q, const float* __restrict__ K,
               const float* __restrict__ V, float* __restrict__ out) {
    __shared__ float attn_lds[BATCH][8][64];
    const int tid = threadIdx.x;
    const int lane_k = tid & 63, row_q = tid >> 6, lane_d = tid & 63;
    const int q0 = blockIdx.x * 8;
    float acc[BATCH];
    #pragma unroll
    for (int b = 0; b < BATCH; ++b) acc[b] = 0.0f;
    for (int k0 = 0; k0 < SEQ; k0 += 64) {
        float s[BATCH];
        #pragma unroll
        for (int b = 0; b < BATCH; ++b) {
            const float4* qrow = (const float4*)(Q + ((size_t)b * SEQ + (q0 + row_q)) * DIM);
            const float4* krow = (const float4*)(K + ((size_t)b * SEQ + (k0 + lane_k)) * DIM);
            float a0 = 0.f;
            #pragma unroll
            for (int d4 = 0; d4 < 16; ++d4) {
                float4 qa = qrow[d4]; float4 kb = krow[d4];
                a0 += qa.x*kb.x + qa.y*kb.y + qa.z*kb.z + qa.w*kb.w;
            }
            s[b] = a0 * 0.125f;
        }
        float m = s[0];
        #pragma unroll
        for (int b = 1; b < BATCH; ++b) m = fmaxf(m, s[b]);
        float den = 0.f;
        #pragma unroll
        for (int b = 0; b < BATCH; ++b) { s[b] = __expf(s[b] - m); den += s[b]; }
        const float inv = 1.0f / den;
        #pragma unroll
        for (int b = 0; b < BATCH; ++b) attn_lds[b][row_q][lane_k] = s[b] * inv;
        __syncthreads();
        #pragma unroll
        for (int b = 0; b < BATCH; ++b) {
            const float* vbase = V + ((size_t)b * SEQ + k0) * DIM + lane_d;
            float acc2 = 0.f;
            #pragma unroll 8
            for (int kk = 0; kk < 64; ++kk) acc2 += attn_lds[b][row_q][kk] * vbase[(size_t)kk * DIM];
            acc[b] += acc2;
        }
        __syncthreads();
    }
    #pragma unroll
    for (int b = 0; b < BATCH; ++b)
        out[((size_t)b * SEQ + (q0 + row_q)) * DIM + lane_d] = acc[b];
}

extern "C" void kernel_launch(void* const* d_in, const int* in_sizes, int n_in,
                              void* d_out, int out_size, void* d_ws, size_t ws_size,
                              hipStream_t stream) {
    const float* Q = (const float*)d_in[0];
    const float* K = (const float*)d_in[1];
    const float* V = (const float*)d_in[2];
    float* out = (float*)d_out;

    if (ws_size < WS_NEED) {
        dpa_naive<<<dim3(SEQ / 8), dim3(512), 0, stream>>>(Q, K, V, out);
        return;
    }
    unsigned short* ws = (unsigned short*)d_ws;
    convert_kernel<<<dim3(2560), dim3(256), 0, stream>>>(Q, K, V, ws, out);
    dpa_main<<<dim3(512), dim3(512), 0, stream>>>(ws, ws + 2097152, ws + 4194304, out);
}